// Round 2
// baseline (109.018 us; speedup 1.0000x reference)
//
#include <hip/hip_runtime.h>

// KV Q4 dequantizer, v3b.
// Layout facts (from reference):
//  - packed: [BATCH * N_BLOCKS * 16] int32, each int holds 2 nibbles (low, high)
//  - scale/bias: [BATCH * N_BLOCKS] fp32, one per 32-value block (= 16 packed ints)
//  - output: flat fp32 stream, K then V; out[2p] = low(p)*s+b, out[2p+1] = high(p)*s+b
//
// v2: one int2 per thread -> exactly one float4 store per thread, perfectly
//     coalesced (lane i stores at base+16i).
// v3: unroll x4 with BLOCK-stride (units at base + u*256). Each load/store
//     instruction keeps the perfect lane->base+{8,16}i coalescing of v2, but
//     each lane now has 4 independent load->store chains in flight (MLP from
//     ILP, not just occupancy) and 4x fewer waves. Nontemporal hints keep the
//     ~105 MB/iter stream from thrashing L2; scale/bias stay normally cached.
// v3b: __builtin_nontemporal_* requires native clang vector types, not
//     HIP_vector_type — use ext_vector_type typedefs for the load/store.

#define UNROLL 4
#define BLOCK_THREADS 256

typedef int   v2i __attribute__((ext_vector_type(2)));
typedef float v4f __attribute__((ext_vector_type(4)));

__global__ __launch_bounds__(BLOCK_THREADS) void kv_dequant_kernel(
    const v2i* __restrict__ k_packed, const float* __restrict__ k_scale,
    const float* __restrict__ k_bias,
    const v2i* __restrict__ v_packed, const float* __restrict__ v_scale,
    const float* __restrict__ v_bias,
    v4f* __restrict__ out_k, v4f* __restrict__ out_v, int n2)
{
    const v2i*   src;
    const float* sc;
    const float* bi;
    v4f*         dst;
    if (blockIdx.y == 0) { src = k_packed; sc = k_scale; bi = k_bias; dst = out_k; }
    else                 { src = v_packed; sc = v_scale; bi = v_bias; dst = out_v; }

    int base = blockIdx.x * (BLOCK_THREADS * UNROLL) + threadIdx.x;

    v2i   p[UNROLL];
    float s[UNROLL];
    float b[UNROLL];
    bool  ok[UNROLL];

    // Issue all packed loads first: 4 independent vmem ops in flight per lane.
#pragma unroll
    for (int u = 0; u < UNROLL; ++u) {
        int t = base + u * BLOCK_THREADS;
        ok[u] = (t < n2);
        if (ok[u]) p[u] = __builtin_nontemporal_load(&src[t]);
    }

    // Scale/bias: 8 lanes share one entry; L1/L2 broadcast handles the reuse.
#pragma unroll
    for (int u = 0; u < UNROLL; ++u) {
        int t = base + u * BLOCK_THREADS;
        if (ok[u]) {
            int blk = t >> 3;   // 2 packed ints/thread-unit, 16 per quant block
            s[u] = sc[blk];
            b[u] = bi[blk];
        }
    }

#pragma unroll
    for (int u = 0; u < UNROLL; ++u) {
        if (!ok[u]) continue;
        int t = base + u * BLOCK_THREADS;
        v4f f;
        f.x = fmaf((float)( p[u].x       & 15), s[u], b[u]);
        f.y = fmaf((float)((p[u].x >> 4) & 15), s[u], b[u]);
        f.z = fmaf((float)( p[u].y       & 15), s[u], b[u]);
        f.w = fmaf((float)((p[u].y >> 4) & 15), s[u], b[u]);
        __builtin_nontemporal_store(f, &dst[t]);
    }
}

extern "C" void kernel_launch(void* const* d_in, const int* in_sizes, int n_in,
                              void* d_out, int out_size, void* d_ws, size_t ws_size,
                              hipStream_t stream) {
    const v2i*   k_packed = (const v2i*)d_in[0];
    const float* k_scale  = (const float*)d_in[1];
    const float* k_bias   = (const float*)d_in[2];
    const v2i*   v_packed = (const v2i*)d_in[3];
    const float* v_scale  = (const float*)d_in[4];
    const float* v_bias   = (const float*)d_in[5];

    int n_packed = in_sizes[0];        // total int32s in k_packed (= v_packed)
    int n2       = n_packed / 2;       // int2 units per tensor
    long long k_out_elems = (long long)n_packed * 2;  // 2 floats per packed int

    v4f* out_k = (v4f*)d_out;
    v4f* out_v = (v4f*)((float*)d_out + k_out_elems);

    const int units_per_block = BLOCK_THREADS * UNROLL;
    dim3 block(BLOCK_THREADS);
    dim3 grid((n2 + units_per_block - 1) / units_per_block, 2);
    kv_dequant_kernel<<<grid, block, 0, stream>>>(
        k_packed, k_scale, k_bias, v_packed, v_scale, v_bias, out_k, out_v, n2);
}

// Round 3
// 107.456 us; speedup vs baseline: 1.0145x; 1.0145x over previous
//
#include <hip/hip_runtime.h>

// KV Q4 dequantizer, v4.
// Layout facts (from reference):
//  - packed: [BATCH * N_BLOCKS * 16] int32, each int holds 2 nibbles (low, high)
//  - scale/bias: [BATCH * N_BLOCKS] fp32, one per 32-value block (= 16 packed ints)
//  - output: flat fp32 stream, K then V; out[2p] = low(p)*s+b, out[2p+1] = high(p)*s+b
//
// v2: one int2 per thread -> exactly one float4 store per thread, perfectly
//     coalesced (lane i stores at base+16i).  105.4 us
// v3b: x4 unroll + nontemporal loads AND stores. REGRESSED to 109.0 us:
//     NT loads forced ~33.6 MB of packed input to re-fetch from HBM each
//     iteration instead of hitting L2/L3 (inputs are only 37.8 MB, partially
//     resident across iterations). Unroll gave nothing (occupancy already
//     provides MLP).
// v4: v2 structure + asymmetric cache policy: CACHED loads (keep input
//     residency), NONTEMPORAL stores only (the 67 MB output stream is never
//     re-read by us; writing around L2 stops it evicting the input lines).

typedef int   v2i __attribute__((ext_vector_type(2)));
typedef float v4f __attribute__((ext_vector_type(4)));

__global__ __launch_bounds__(256) void kv_dequant_kernel(
    const v2i* __restrict__ k_packed, const float* __restrict__ k_scale,
    const float* __restrict__ k_bias,
    const v2i* __restrict__ v_packed, const float* __restrict__ v_scale,
    const float* __restrict__ v_bias,
    v4f* __restrict__ out_k, v4f* __restrict__ out_v, int n2)
{
    int tid = blockIdx.x * blockDim.x + threadIdx.x;
    if (tid >= n2) return;

    const v2i*   src;
    const float* sc;
    const float* bi;
    v4f*         dst;
    if (blockIdx.y == 0) { src = k_packed; sc = k_scale; bi = k_bias; dst = out_k; }
    else                 { src = v_packed; sc = v_scale; bi = v_bias; dst = out_v; }

    v2i p = src[tid];                 // cached load: input may be L2/L3-resident

    // 2 packed ints per thread, 16 packed ints per quant block -> block idx = tid/8
    int blk = tid >> 3;
    float s = sc[blk];
    float b = bi[blk];

    v4f f;
    f.x = fmaf((float)( p.x       & 15), s, b);
    f.y = fmaf((float)((p.x >> 4) & 15), s, b);
    f.z = fmaf((float)( p.y       & 15), s, b);
    f.w = fmaf((float)((p.y >> 4) & 15), s, b);

    __builtin_nontemporal_store(f, &dst[tid]);   // streaming store: don't pollute L2
}

extern "C" void kernel_launch(void* const* d_in, const int* in_sizes, int n_in,
                              void* d_out, int out_size, void* d_ws, size_t ws_size,
                              hipStream_t stream) {
    const v2i*   k_packed = (const v2i*)d_in[0];
    const float* k_scale  = (const float*)d_in[1];
    const float* k_bias   = (const float*)d_in[2];
    const v2i*   v_packed = (const v2i*)d_in[3];
    const float* v_scale  = (const float*)d_in[4];
    const float* v_bias   = (const float*)d_in[5];

    int n_packed = in_sizes[0];        // total int32s in k_packed (= v_packed)
    int n2       = n_packed / 2;       // int2 units per tensor
    long long k_out_elems = (long long)n_packed * 2;  // 2 floats per packed int

    v4f* out_k = (v4f*)d_out;
    v4f* out_v = (v4f*)((float*)d_out + k_out_elems);

    dim3 block(256);
    dim3 grid((n2 + 255) / 256, 2);
    kv_dequant_kernel<<<grid, block, 0, stream>>>(
        k_packed, k_scale, k_bias, v_packed, v_scale, v_bias, out_k, out_v, n2);
}

// Round 4
// 104.866 us; speedup vs baseline: 1.0396x; 1.0247x over previous
//
#include <hip/hip_runtime.h>

// KV Q4 dequantizer, v5 (= v2 exact revert — best measured: 105.4 us).
// Layout facts (from reference):
//  - packed: [BATCH * N_BLOCKS * 16] int32, each int holds 2 nibbles (low, high)
//  - scale/bias: [BATCH * N_BLOCKS] fp32, one per 32-value block (= 16 packed ints)
//  - output: flat fp32 stream, K then V; out[2p] = low(p)*s+b, out[2p+1] = high(p)*s+b
//
// Experiment log:
//  v2: one int2 per thread -> one float4 store, perfectly coalesced. 105.4 us.
//  v3b: x4 unroll + NT loads + NT stores.  109.0 us  (REGRESSED)
//  v4: NT stores only.                     107.5 us  (REGRESSED)
// Post-mortem: the harness's poison fills write 268 MB (> 256 MiB L3) between
// iterations, flushing all caches — there is no input residency to protect,
// and NT hints only constrain the hardware. Default cache policy wins.
// Kernel moves ~105 MB -> ~16.6 us floor @ 6.3 TB/s; measured ~22 us (~78%
// of achievable for a mixed R+W stream). Remaining dur_us is the harness's
// own HBM-bound fill dispatches (~83 us). This is the roofline.

__global__ __launch_bounds__(256) void kv_dequant_kernel(
    const int2* __restrict__ k_packed, const float* __restrict__ k_scale,
    const float* __restrict__ k_bias,
    const int2* __restrict__ v_packed, const float* __restrict__ v_scale,
    const float* __restrict__ v_bias,
    float4* __restrict__ out_k, float4* __restrict__ out_v, int n2)
{
    int tid = blockIdx.x * blockDim.x + threadIdx.x;
    if (tid >= n2) return;

    const int2*  src;
    const float* sc;
    const float* bi;
    float4*      dst;
    if (blockIdx.y == 0) { src = k_packed; sc = k_scale; bi = k_bias; dst = out_k; }
    else                 { src = v_packed; sc = v_scale; bi = v_bias; dst = out_v; }

    int2 p = src[tid];

    // 2 packed ints per thread, 16 packed ints per quant block -> block idx = tid/8
    int blk = tid >> 3;
    float s = sc[blk];
    float b = bi[blk];

    float4 f;
    f.x = fmaf((float)( p.x       & 15), s, b);
    f.y = fmaf((float)((p.x >> 4) & 15), s, b);
    f.z = fmaf((float)( p.y       & 15), s, b);
    f.w = fmaf((float)((p.y >> 4) & 15), s, b);

    dst[tid] = f;
}

extern "C" void kernel_launch(void* const* d_in, const int* in_sizes, int n_in,
                              void* d_out, int out_size, void* d_ws, size_t ws_size,
                              hipStream_t stream) {
    const int2*  k_packed = (const int2*)d_in[0];
    const float* k_scale  = (const float*)d_in[1];
    const float* k_bias   = (const float*)d_in[2];
    const int2*  v_packed = (const int2*)d_in[3];
    const float* v_scale  = (const float*)d_in[4];
    const float* v_bias   = (const float*)d_in[5];

    int n_packed = in_sizes[0];        // total int32s in k_packed (= v_packed)
    int n2       = n_packed / 2;       // int2 units per tensor
    long long k_out_elems = (long long)n_packed * 2;  // 2 floats per packed int

    float4* out_k = (float4*)d_out;
    float4* out_v = (float4*)((float*)d_out + k_out_elems);

    dim3 block(256);
    dim3 grid((n2 + 255) / 256, 2);
    kv_dequant_kernel<<<grid, block, 0, stream>>>(
        k_packed, k_scale, k_bias, v_packed, v_scale, v_bias, out_k, out_v, n2);
}